// Round 1
// baseline (290.145 us; speedup 1.0000x reference)
//
#include <hip/hip_runtime.h>
#include <stdint.h>

// MeshPoolFace: batched segment-mean pooling.
// fe: [B=16, C=256, F=16000] f32, gid: [B, F] int32 in [0, T=8000)
// out[b][c][t] = mean over {f : gid[b][f]==t} of fe[b][c][f]
//
// Round-8: pipeline the pool. Evidence: harness fill kernels sustain 7 TB/s;
// min traffic 393 MB -> 56us floor; round-7 was 127us (45% of roofline) with
// a serial 3-phase chain (HBM idle during LDS phases). New pool:
//   - 8 channels/block, grid=512 (exactly 2 blocks/CU, persistent)
//   - sp/pk/gorder register-cached ONCE per block (reused x8 channels)
//   - fes double-buffered (2x32KB), depth-1 prefetch: ch k+1 loads issued
//     BEFORE ds_write of ch k -> loads in flight across write+barrier+compute
//   - means stored directly to global (scattered dword; out row is 32KB,
//     L2-resident, every element written exactly once -> lines fully dirty,
//     no write amplification). Kills outs LDS + flush phase + one barrier.

#define NB 16
#define NC 256
#define NF 16000
#define NT 8000
#define CPB 8   // channels per pool block; grid = NB * NC/CPB = 512

typedef unsigned int uint;
typedef unsigned short ushort;

__device__ __forceinline__ uint bf16rne(float x) {
    uint u = __float_as_uint(x);
    return (u + 0x7FFFu + ((u >> 16) & 1u)) >> 16;
}
__device__ __forceinline__ float bf2f(uint h) { return __uint_as_float(h << 16); }

// K1: global histogram of group sizes. grid = 250.
__global__ __launch_bounds__(256) void hist_kernel(const int* __restrict__ gid,
                                                   int* __restrict__ cnt) {
    int i = blockIdx.x * 256 + threadIdx.x;
    if (i >= NB * NF / 4) return;
    int4 g = ((const int4*)gid)[i];
    int* c = cnt + (i / (NF / 4)) * NT;
    atomicAdd(&c[g.x], 1);
    atomicAdd(&c[g.y], 1);
    atomicAdd(&c[g.z], 1);
    atomicAdd(&c[g.w], 1);
}

// K2: per batch (grid=NB): exclusive scan of cnt -> off; size-sorted rank
// order: gorder (rank->t), pk (rank -> off | n<<14); cursor = off copy.
__global__ __launch_bounds__(256) void scan_rank_kernel(const int* __restrict__ cnt_g,
                                                        uint* __restrict__ pk,
                                                        uint* __restrict__ cursor,
                                                        ushort* __restrict__ gorder) {
    __shared__ int off_s[NT];
    __shared__ int partial[256];
    __shared__ int hist2[65];
    __shared__ int cur2[65];
    const int b = blockIdx.x, tid = threadIdx.x;
    const int* cnt = cnt_g + b * NT;

    int loc[32];
    int ts = 0;
    if (tid < 250) {
        const int4* c4 = (const int4*)(cnt + 32 * tid);
#pragma unroll
        for (int j = 0; j < 8; ++j) {
            int4 v = c4[j];
            loc[4 * j + 0] = ts; ts += v.x;
            loc[4 * j + 1] = ts; ts += v.y;
            loc[4 * j + 2] = ts; ts += v.z;
            loc[4 * j + 3] = ts; ts += v.w;
        }
    }
    partial[tid] = (tid < 250) ? ts : 0;
    if (tid < 65) hist2[tid] = 0;
    __syncthreads();

    if (tid < 64) {
        int s0 = partial[4 * tid], s1 = partial[4 * tid + 1];
        int s2 = partial[4 * tid + 2], s3 = partial[4 * tid + 3];
        int lsum = s0 + s1 + s2 + s3;
        int inc = lsum;
        for (int d = 1; d < 64; d <<= 1) {
            int u = __shfl_up(inc, d);
            if (tid >= d) inc += u;
        }
        int exc = inc - lsum;
        partial[4 * tid + 0] = exc;
        partial[4 * tid + 1] = exc + s0;
        partial[4 * tid + 2] = exc + s0 + s1;
        partial[4 * tid + 3] = exc + s0 + s1 + s2;
    }
    __syncthreads();

    if (tid < 250) {
        int base = partial[tid];
#pragma unroll
        for (int j = 0; j < 32; ++j) off_s[32 * tid + j] = base + loc[j];
    }
    __syncthreads();

    for (int t = tid; t < NT; t += 256) {
        int n = cnt[t];
        atomicAdd(&hist2[n > 64 ? 64 : n], 1);
    }
    __syncthreads();
    if (tid == 0) {
        int s = 0;
        for (int i = 0; i < 65; ++i) { int h = hist2[i]; cur2[i] = s; s += h; }
    }
    __syncthreads();

    uint* pkb = pk + (size_t)b * NT;
    uint* cb = cursor + (size_t)b * NT;
    ushort* gb = gorder + (size_t)b * NT;
    for (int t = tid; t < NT; t += 256) {
        int n = cnt[t];
        int o = off_s[t];
        int rnk = atomicAdd(&cur2[n > 64 ? 64 : n], 1);
        gb[rnk] = (ushort)t;
        pkb[rnk] = (uint)o | ((uint)n << 14);      // off < 16384, n < 2^18
        cb[t] = (uint)o;
    }
}

// K3: compute INVERSE permutation sp[b][f] = sorted position of face f.
__global__ __launch_bounds__(256) void invperm_kernel(const int* __restrict__ gid,
                                                      uint* __restrict__ cursor,
                                                      ushort* __restrict__ sp) {
    const int b = blockIdx.x >> 2, q = blockIdx.x & 3;
    const int4* g4 = (const int4*)(gid + (size_t)b * NF + q * (NF / 4));
    uint* cb = cursor + (size_t)b * NT;
    uint2* sp2 = (uint2*)(sp + (size_t)b * NF + q * (NF / 4));  // 8B aligned
    for (int i = threadIdx.x; i < NF / 16; i += 256) {
        int4 g = g4[i];
        uint p0 = atomicAdd(&cb[g.x], 1u);
        uint p1 = atomicAdd(&cb[g.y], 1u);
        uint p2 = atomicAdd(&cb[g.z], 1u);
        uint p3 = atomicAdd(&cb[g.w], 1u);
        sp2[i] = make_uint2(p0 | (p1 << 16), p2 | (p3 << 16));
    }
}

// K4: pipelined pool. grid = NB * NC/CPB = 512 blocks, 1024 thr,
// 64 KB LDS (fes double buffer) -> 2 blocks/CU, 32 waves/CU.
// Per block: 8 channels of one batch; 1 barrier per channel.
__global__ __launch_bounds__(1024, 8) void pool_kernel(const float* __restrict__ fe,
                                                       const ushort* __restrict__ sp,
                                                       const uint* __restrict__ pk,
                                                       const ushort* __restrict__ gorder,
                                                       float* __restrict__ out) {
    __shared__ ushort fes[2][16384];   // 2 x 32 KB, sorted-order bf16 fe row
    const int bid = blockIdx.x;
    const int b = bid >> 5, cg = bid & 31;
    const int tid = threadIdx.x;
    const size_t bc0 = (size_t)(b * NC + cg * CPB);

    // Register-cache the inverse permutation for this thread's faces.
    // Thread owns float4 indices {tid, tid+1024, tid+2048, tid+3072(<928)}.
    const uint2* sp2 = (const uint2*)(sp + (size_t)b * NF);
    uint2 s0 = sp2[tid];
    uint2 s1 = sp2[tid + 1024];
    uint2 s2 = sp2[tid + 2048];
    uint2 s3 = make_uint2(0u, 0u);
    if (tid < 928) s3 = sp2[tid + 3072];

    // Register-cache pk/gorder for this thread's groups (ranks
    // {tid+it*1024, it<7} + {7168+tid, tid<832}).
    const uint* pkb = pk + (size_t)b * NT;
    const ushort* gob = gorder + (size_t)b * NT;
    uint pv[8], gv[8];
#pragma unroll
    for (int it = 0; it < 7; ++it) {
        pv[it] = pkb[tid + it * 1024];
        gv[it] = gob[tid + it * 1024];
    }
    pv[7] = 0; gv[7] = 0;
    if (tid < 832) { pv[7] = pkb[7168 + tid]; gv[7] = gob[7168 + tid]; }

    const float4* fe4base = (const float4*)(fe + bc0 * NF);
    float4 va0, va1, va2, va3, vb0, vb1, vb2, vb3;

#define LOADC(k, V0, V1, V2, V3) do {                                   \
        const float4* f4_ = fe4base + (size_t)(k) * (NF / 4);           \
        V0 = f4_[tid];                                                  \
        V1 = f4_[tid + 1024];                                           \
        V2 = f4_[tid + 2048];                                           \
        if (tid < 928) V3 = f4_[tid + 3072];                            \
    } while (0)

#define WRITEC(buf, V0, V1, V2, V3) do {                                \
        ushort* F_ = fes[buf];                                          \
        F_[s0.x & 0xFFFFu] = (ushort)bf16rne(V0.x);                     \
        F_[s0.x >> 16]     = (ushort)bf16rne(V0.y);                     \
        F_[s0.y & 0xFFFFu] = (ushort)bf16rne(V0.z);                     \
        F_[s0.y >> 16]     = (ushort)bf16rne(V0.w);                     \
        F_[s1.x & 0xFFFFu] = (ushort)bf16rne(V1.x);                     \
        F_[s1.x >> 16]     = (ushort)bf16rne(V1.y);                     \
        F_[s1.y & 0xFFFFu] = (ushort)bf16rne(V1.z);                     \
        F_[s1.y >> 16]     = (ushort)bf16rne(V1.w);                     \
        F_[s2.x & 0xFFFFu] = (ushort)bf16rne(V2.x);                     \
        F_[s2.x >> 16]     = (ushort)bf16rne(V2.y);                     \
        F_[s2.y & 0xFFFFu] = (ushort)bf16rne(V2.z);                     \
        F_[s2.y >> 16]     = (ushort)bf16rne(V2.w);                     \
        if (tid < 928) {                                                \
            F_[s3.x & 0xFFFFu] = (ushort)bf16rne(V3.x);                 \
            F_[s3.x >> 16]     = (ushort)bf16rne(V3.y);                 \
            F_[s3.y & 0xFFFFu] = (ushort)bf16rne(V3.z);                 \
            F_[s3.y >> 16]     = (ushort)bf16rne(V3.w);                 \
        }                                                               \
    } while (0)

#define GRP(it) do {                                                    \
        uint p_ = pv[it];                                               \
        uint off_ = p_ & 0x3FFFu, n_ = p_ >> 14;                        \
        float sacc_ = 0.f;                                              \
        for (uint r_ = 0; r_ < n_; ++r_)                                \
            sacc_ += bf2f((uint)F_[off_ + r_]);                         \
        orow_[gv[it]] =                                                 \
            n_ ? sacc_ * __builtin_amdgcn_rcpf((float)n_) : 0.f;        \
    } while (0)

#define COMPC(k, buf) do {                                              \
        const ushort* F_ = fes[buf];                                    \
        float* orow_ = out + (bc0 + (k)) * NT;                          \
        GRP(0); GRP(1); GRP(2); GRP(3); GRP(4); GRP(5); GRP(6);         \
        if (tid < 832) GRP(7);                                          \
    } while (0)

    // STEP: issue next-channel loads FIRST (in flight across write+barrier+
    // compute), then scatter current channel into its LDS buffer, one
    // barrier, then compute+store. Ping-pong buffers: buffer (k&1) reuse is
    // separated from its readers by the barrier at step k+1.
#define STEP(k, C0, C1, C2, C3, N0, N1, N2, N3) do {                    \
        if ((k) + 1 < CPB) LOADC((k) + 1, N0, N1, N2, N3);              \
        WRITEC((k) & 1, C0, C1, C2, C3);                                \
        __syncthreads();                                                \
        COMPC((k), (k) & 1);                                            \
    } while (0)

    LOADC(0, va0, va1, va2, va3);
    STEP(0, va0, va1, va2, va3, vb0, vb1, vb2, vb3);
    STEP(1, vb0, vb1, vb2, vb3, va0, va1, va2, va3);
    STEP(2, va0, va1, va2, va3, vb0, vb1, vb2, vb3);
    STEP(3, vb0, vb1, vb2, vb3, va0, va1, va2, va3);
    STEP(4, va0, va1, va2, va3, vb0, vb1, vb2, vb3);
    STEP(5, vb0, vb1, vb2, vb3, va0, va1, va2, va3);
    STEP(6, va0, va1, va2, va3, vb0, vb1, vb2, vb3);
    STEP(7, vb0, vb1, vb2, vb3, va0, va1, va2, va3);

#undef STEP
#undef COMPC
#undef GRP
#undef WRITEC
#undef LOADC
}

// Fallback (round-2 path) if workspace is too small.
__device__ __forceinline__ void lds_fadd(unsigned addr, float v) {
    asm volatile("ds_add_f32 %0, %1" :: "v"(addr), "v"(v));
}
__global__ __launch_bounds__(256) void pool_fused_kernel(const float* __restrict__ fe,
                                                         const int* __restrict__ gid,
                                                         float* __restrict__ out) {
    __shared__ float acc[NT];
    __shared__ int cnt[NT];
    const int bc = blockIdx.x, b = bc >> 8, tid = threadIdx.x;
    for (int t = tid; t < NT; t += 256) { acc[t] = 0.0f; cnt[t] = 0; }
    __syncthreads();
    const unsigned accb = (unsigned)(uintptr_t)acc;
    const float4* fe4 = (const float4*)(fe + (size_t)bc * NF);
    const int4* gid4 = (const int4*)(gid + (size_t)b * NF);
    for (int i = tid; i < NF / 4; i += 256) {
        float4 v = fe4[i];
        int4 g = gid4[i];
        lds_fadd(accb + 4u * (unsigned)g.x, v.x); atomicAdd(&cnt[g.x], 1);
        lds_fadd(accb + 4u * (unsigned)g.y, v.y); atomicAdd(&cnt[g.y], 1);
        lds_fadd(accb + 4u * (unsigned)g.z, v.z); atomicAdd(&cnt[g.z], 1);
        lds_fadd(accb + 4u * (unsigned)g.w, v.w); atomicAdd(&cnt[g.w], 1);
    }
    asm volatile("s_waitcnt lgkmcnt(0)" ::: "memory");
    __syncthreads();
    float* orow = out + (size_t)bc * NT;
    for (int t = tid; t < NT; t += 256) {
        int n = cnt[t];
        orow[t] = acc[t] / (float)(n > 0 ? n : 1);
    }
}

extern "C" void kernel_launch(void* const* d_in, const int* in_sizes, int n_in,
                              void* d_out, int out_size, void* d_ws, size_t ws_size,
                              hipStream_t stream) {
    const float* fe = (const float*)d_in[0];
    const int* gid = (const int*)d_in[1];
    float* out = (float*)d_out;

    // workspace layout (bytes)
    const size_t O_CNT = 0;          // int [NB*NT]   512000
    const size_t O_CUR = 512000;     // u32 [NB*NT]   512000
    const size_t O_PK  = 1024000;    // u32 [NB*NT]   512000
    const size_t O_GO  = 1536000;    // u16 [NB*NT]   256000
    const size_t O_SP  = 1792000;    // u16 [NB*NF]   512000
    const size_t TOTAL = 2304000;

    if (ws_size >= TOTAL) {
        char* w = (char*)d_ws;
        int* cnt = (int*)(w + O_CNT);
        uint* cursor = (uint*)(w + O_CUR);
        uint* pk = (uint*)(w + O_PK);
        ushort* gorder = (ushort*)(w + O_GO);
        ushort* sp = (ushort*)(w + O_SP);

        hipMemsetAsync(cnt, 0, 512000, stream);
        hist_kernel<<<(NB * NF / 4 + 255) / 256, 256, 0, stream>>>(gid, cnt);
        scan_rank_kernel<<<NB, 256, 0, stream>>>(cnt, pk, cursor, gorder);
        invperm_kernel<<<NB * 4, 256, 0, stream>>>(gid, cursor, sp);
        pool_kernel<<<NB * (NC / CPB), 1024, 0, stream>>>(fe, sp, pk, gorder, out);
    } else {
        pool_fused_kernel<<<NB * NC, 256, 0, stream>>>(fe, gid, out);
    }
}

// Round 3
// 122.196 us; speedup vs baseline: 2.3744x; 2.3744x over previous
//
#include <hip/hip_runtime.h>
#include <stdint.h>

// MeshPoolFace: batched segment-mean pooling.
// fe: [B=16, C=256, F=16000] f32, gid: [B, F] int32 in [0, T=8000)
// out[b][c][t] = mean over {f : gid[b][f]==t} of fe[b][c][f]
//
// Round-10 = round-9 with the compile fix: __builtin_nontemporal_* requires
// clang ext_vector types, not HIP_vector_type<float,4>. Use f32x4.
//
// Round-9 design notes: round-8 post-mortem showed __launch_bounds__(1024,8)
// clamped VGPRs to 32 -> full scratch spill (~1 GB junk traffic); scattered
// global stores amplified WRITE 4.6x. Fix: plain launch_bounds, single-buffer
// pipeline (16 data VGPRs in flight), LDS outs + nontemporal coalesced flush.
// Keep CPB=8 (metadata register-cached once, reused x8) and depth-1 prefetch
// (ch k+1 loads issued before the P1 sum of ch k).
// Per channel: WRITE(regs->fes) / bar / LOAD(k+1)+P1(sum->outs) / bar /
// FLUSH(outs->out, nontemporal f32x4). 2 barriers/channel.

#define NB 16
#define NC 256
#define NF 16000
#define NT 8000
#define CPB 8   // channels per pool block; grid = NB * NC/CPB = 512

typedef unsigned int uint;
typedef unsigned short ushort;
typedef float f32x4 __attribute__((ext_vector_type(4)));

__device__ __forceinline__ uint bf16rne(float x) {
    uint u = __float_as_uint(x);
    return (u + 0x7FFFu + ((u >> 16) & 1u)) >> 16;
}
__device__ __forceinline__ float bf2f(uint h) { return __uint_as_float(h << 16); }

// K1: global histogram of group sizes. grid = 250.
__global__ __launch_bounds__(256) void hist_kernel(const int* __restrict__ gid,
                                                   int* __restrict__ cnt) {
    int i = blockIdx.x * 256 + threadIdx.x;
    if (i >= NB * NF / 4) return;
    int4 g = ((const int4*)gid)[i];
    int* c = cnt + (i / (NF / 4)) * NT;
    atomicAdd(&c[g.x], 1);
    atomicAdd(&c[g.y], 1);
    atomicAdd(&c[g.z], 1);
    atomicAdd(&c[g.w], 1);
}

// K2: per batch (grid=NB): exclusive scan of cnt -> off; size-sorted rank
// order: gorder (rank->t), pk (rank -> off | n<<14); cursor = off copy.
__global__ __launch_bounds__(256) void scan_rank_kernel(const int* __restrict__ cnt_g,
                                                        uint* __restrict__ pk,
                                                        uint* __restrict__ cursor,
                                                        ushort* __restrict__ gorder) {
    __shared__ int off_s[NT];
    __shared__ int partial[256];
    __shared__ int hist2[65];
    __shared__ int cur2[65];
    const int b = blockIdx.x, tid = threadIdx.x;
    const int* cnt = cnt_g + b * NT;

    int loc[32];
    int ts = 0;
    if (tid < 250) {
        const int4* c4 = (const int4*)(cnt + 32 * tid);
#pragma unroll
        for (int j = 0; j < 8; ++j) {
            int4 v = c4[j];
            loc[4 * j + 0] = ts; ts += v.x;
            loc[4 * j + 1] = ts; ts += v.y;
            loc[4 * j + 2] = ts; ts += v.z;
            loc[4 * j + 3] = ts; ts += v.w;
        }
    }
    partial[tid] = (tid < 250) ? ts : 0;
    if (tid < 65) hist2[tid] = 0;
    __syncthreads();

    if (tid < 64) {
        int s0 = partial[4 * tid], s1 = partial[4 * tid + 1];
        int s2 = partial[4 * tid + 2], s3 = partial[4 * tid + 3];
        int lsum = s0 + s1 + s2 + s3;
        int inc = lsum;
        for (int d = 1; d < 64; d <<= 1) {
            int u = __shfl_up(inc, d);
            if (tid >= d) inc += u;
        }
        int exc = inc - lsum;
        partial[4 * tid + 0] = exc;
        partial[4 * tid + 1] = exc + s0;
        partial[4 * tid + 2] = exc + s0 + s1;
        partial[4 * tid + 3] = exc + s0 + s1 + s2;
    }
    __syncthreads();

    if (tid < 250) {
        int base = partial[tid];
#pragma unroll
        for (int j = 0; j < 32; ++j) off_s[32 * tid + j] = base + loc[j];
    }
    __syncthreads();

    for (int t = tid; t < NT; t += 256) {
        int n = cnt[t];
        atomicAdd(&hist2[n > 64 ? 64 : n], 1);
    }
    __syncthreads();
    if (tid == 0) {
        int s = 0;
        for (int i = 0; i < 65; ++i) { int h = hist2[i]; cur2[i] = s; s += h; }
    }
    __syncthreads();

    uint* pkb = pk + (size_t)b * NT;
    uint* cb = cursor + (size_t)b * NT;
    ushort* gb = gorder + (size_t)b * NT;
    for (int t = tid; t < NT; t += 256) {
        int n = cnt[t];
        int o = off_s[t];
        int rnk = atomicAdd(&cur2[n > 64 ? 64 : n], 1);
        gb[rnk] = (ushort)t;
        pkb[rnk] = (uint)o | ((uint)n << 14);      // off < 16384, n < 2^18
        cb[t] = (uint)o;
    }
}

// K3: compute INVERSE permutation sp[b][f] = sorted position of face f.
__global__ __launch_bounds__(256) void invperm_kernel(const int* __restrict__ gid,
                                                      uint* __restrict__ cursor,
                                                      ushort* __restrict__ sp) {
    const int b = blockIdx.x >> 2, q = blockIdx.x & 3;
    const int4* g4 = (const int4*)(gid + (size_t)b * NF + q * (NF / 4));
    uint* cb = cursor + (size_t)b * NT;
    uint2* sp2 = (uint2*)(sp + (size_t)b * NF + q * (NF / 4));  // 8B aligned
    for (int i = threadIdx.x; i < NF / 16; i += 256) {
        int4 g = g4[i];
        uint p0 = atomicAdd(&cb[g.x], 1u);
        uint p1 = atomicAdd(&cb[g.y], 1u);
        uint p2 = atomicAdd(&cb[g.z], 1u);
        uint p3 = atomicAdd(&cb[g.w], 1u);
        sp2[i] = make_uint2(p0 | (p1 << 16), p2 | (p3 << 16));
    }
}

// K4: pipelined pool. grid = NB * NC/CPB = 512 blocks, 1024 thr,
// 64 KB LDS (fes 32K + outs 32K). No forced occupancy bound (round-8
// lesson: the bound caused a 32-VGPR clamp and full scratch spill).
__global__ __launch_bounds__(1024) void pool_kernel(const float* __restrict__ fe,
                                                    const ushort* __restrict__ sp,
                                                    const uint* __restrict__ pk,
                                                    const ushort* __restrict__ gorder,
                                                    float* __restrict__ out) {
    __shared__ ushort fes[16384];   // 32 KB: fe row bf16, sorted by group
    __shared__ float outs[NT];      // 32 KB: pooled means, group-id order
    const int bid = blockIdx.x;
    const int b = bid >> 5, cg = bid & 31;
    const int tid = threadIdx.x;
    const size_t bc0 = (size_t)(b * NC + cg * CPB);
    const bool tail = (tid < 928);
    const bool tail2 = (tid < 832);

    // Register-cache inverse permutation for this thread's faces
    // (float4 indices {tid, tid+1024, tid+2048, tid+3072(<928)}). 7 VGPRs.
    const uint2* sp2 = (const uint2*)(sp + (size_t)b * NF);
    uint2 s0 = sp2[tid];
    uint2 s1 = sp2[tid + 1024];
    uint2 s2 = sp2[tid + 2048];
    uint2 s3 = make_uint2(0u, 0u);
    if (tail) s3 = sp2[tid + 3072];

    // Register-cache pk/gorder for this thread's groups (ranks
    // {tid+it*1024, it<7} + {7168+tid, tid<832}). Reused for all 8 channels.
    const uint* pkb = pk + (size_t)b * NT;
    const ushort* gob = gorder + (size_t)b * NT;
    uint pv[8];
    ushort gv[8];
#pragma unroll
    for (int it = 0; it < 7; ++it) {
        pv[it] = pkb[tid + it * 1024];
        gv[it] = gob[tid + it * 1024];
    }
    pv[7] = 0; gv[7] = 0;
    if (tail2) { pv[7] = pkb[7168 + tid]; gv[7] = gob[7168 + tid]; }

    const f32x4* fe4base = (const f32x4*)(fe + bc0 * NF);
    f32x4 n0, n1, n2, n3;
    n3 = (f32x4)(0.f);

    // prologue: issue channel-0 loads
    {
        const f32x4* f4 = fe4base;
        n0 = __builtin_nontemporal_load(&f4[tid]);
        n1 = __builtin_nontemporal_load(&f4[tid + 1024]);
        n2 = __builtin_nontemporal_load(&f4[tid + 2048]);
        if (tail) n3 = __builtin_nontemporal_load(&f4[tid + 3072]);
    }

#pragma unroll
    for (int k = 0; k < CPB; ++k) {
        // scatter channel k (in regs) into fes. fes free: barrier at end of
        // previous iteration ordered all P1 reads before this.
        fes[s0.x & 0xFFFFu] = (ushort)bf16rne(n0[0]);
        fes[s0.x >> 16]     = (ushort)bf16rne(n0[1]);
        fes[s0.y & 0xFFFFu] = (ushort)bf16rne(n0[2]);
        fes[s0.y >> 16]     = (ushort)bf16rne(n0[3]);
        fes[s1.x & 0xFFFFu] = (ushort)bf16rne(n1[0]);
        fes[s1.x >> 16]     = (ushort)bf16rne(n1[1]);
        fes[s1.y & 0xFFFFu] = (ushort)bf16rne(n1[2]);
        fes[s1.y >> 16]     = (ushort)bf16rne(n1[3]);
        fes[s2.x & 0xFFFFu] = (ushort)bf16rne(n2[0]);
        fes[s2.x >> 16]     = (ushort)bf16rne(n2[1]);
        fes[s2.y & 0xFFFFu] = (ushort)bf16rne(n2[2]);
        fes[s2.y >> 16]     = (ushort)bf16rne(n2[3]);
        if (tail) {
            fes[s3.x & 0xFFFFu] = (ushort)bf16rne(n3[0]);
            fes[s3.x >> 16]     = (ushort)bf16rne(n3[1]);
            fes[s3.y & 0xFFFFu] = (ushort)bf16rne(n3[2]);
            fes[s3.y >> 16]     = (ushort)bf16rne(n3[3]);
        }
        __syncthreads();   // fes ready; prev flush done -> outs writable

        // issue channel k+1 loads: in flight across P1 + barrier + flush
        if (k + 1 < CPB) {
            const f32x4* f4 = fe4base + (size_t)(k + 1) * (NF / 4);
            n0 = __builtin_nontemporal_load(&f4[tid]);
            n1 = __builtin_nontemporal_load(&f4[tid + 1024]);
            n2 = __builtin_nontemporal_load(&f4[tid + 2048]);
            if (tail) n3 = __builtin_nontemporal_load(&f4[tid + 3072]);
        }

        // P1: size-sorted ranks -> wave-uniform n; scatter mean to outs.
#pragma unroll
        for (int it = 0; it < 7; ++it) {
            uint p = pv[it];
            uint off = p & 0x3FFFu, n = p >> 14;
            float s = 0.f;
            for (uint r = 0; r < n; ++r) s += bf2f((uint)fes[off + r]);
            outs[gv[it]] = n ? s * __builtin_amdgcn_rcpf((float)n) : 0.f;
        }
        if (tail2) {
            uint p = pv[7];
            uint off = p & 0x3FFFu, n = p >> 14;
            float s = 0.f;
            for (uint r = 0; r < n; ++r) s += bf2f((uint)fes[off + r]);
            outs[gv[7]] = n ? s * __builtin_amdgcn_rcpf((float)n) : 0.f;
        }
        __syncthreads();   // outs ready; fes fully consumed

        // flush outs -> out row k, coalesced nontemporal f32x4 (full lines,
        // write-once: keep out of L2 so the fe stream isn't evicting
        // partially-dirty lines -- round-8's WRITE amplification).
        {
            const f32x4* os4 = (const f32x4*)outs;
            f32x4* o4 = (f32x4*)(out + (bc0 + (size_t)k) * NT);
            __builtin_nontemporal_store(os4[tid], &o4[tid]);
            if (tid < 976)
                __builtin_nontemporal_store(os4[1024 + tid], &o4[1024 + tid]);
        }
    }
}

// Fallback (round-2 path) if workspace is too small.
__device__ __forceinline__ void lds_fadd(unsigned addr, float v) {
    asm volatile("ds_add_f32 %0, %1" :: "v"(addr), "v"(v));
}
__global__ __launch_bounds__(256) void pool_fused_kernel(const float* __restrict__ fe,
                                                         const int* __restrict__ gid,
                                                         float* __restrict__ out) {
    __shared__ float acc[NT];
    __shared__ int cnt[NT];
    const int bc = blockIdx.x, b = bc >> 8, tid = threadIdx.x;
    for (int t = tid; t < NT; t += 256) { acc[t] = 0.0f; cnt[t] = 0; }
    __syncthreads();
    const unsigned accb = (unsigned)(uintptr_t)acc;
    const float4* fe4 = (const float4*)(fe + (size_t)bc * NF);
    const int4* gid4 = (const int4*)(gid + (size_t)b * NF);
    for (int i = tid; i < NF / 4; i += 256) {
        float4 v = fe4[i];
        int4 g = gid4[i];
        lds_fadd(accb + 4u * (unsigned)g.x, v.x); atomicAdd(&cnt[g.x], 1);
        lds_fadd(accb + 4u * (unsigned)g.y, v.y); atomicAdd(&cnt[g.y], 1);
        lds_fadd(accb + 4u * (unsigned)g.z, v.z); atomicAdd(&cnt[g.z], 1);
        lds_fadd(accb + 4u * (unsigned)g.w, v.w); atomicAdd(&cnt[g.w], 1);
    }
    asm volatile("s_waitcnt lgkmcnt(0)" ::: "memory");
    __syncthreads();
    float* orow = out + (size_t)bc * NT;
    for (int t = tid; t < NT; t += 256) {
        int n = cnt[t];
        orow[t] = acc[t] / (float)(n > 0 ? n : 1);
    }
}

extern "C" void kernel_launch(void* const* d_in, const int* in_sizes, int n_in,
                              void* d_out, int out_size, void* d_ws, size_t ws_size,
                              hipStream_t stream) {
    const float* fe = (const float*)d_in[0];
    const int* gid = (const int*)d_in[1];
    float* out = (float*)d_out;

    // workspace layout (bytes)
    const size_t O_CNT = 0;          // int [NB*NT]   512000
    const size_t O_CUR = 512000;     // u32 [NB*NT]   512000
    const size_t O_PK  = 1024000;    // u32 [NB*NT]   512000
    const size_t O_GO  = 1536000;    // u16 [NB*NT]   256000
    const size_t O_SP  = 1792000;    // u16 [NB*NF]   512000
    const size_t TOTAL = 2304000;

    if (ws_size >= TOTAL) {
        char* w = (char*)d_ws;
        int* cnt = (int*)(w + O_CNT);
        uint* cursor = (uint*)(w + O_CUR);
        uint* pk = (uint*)(w + O_PK);
        ushort* gorder = (ushort*)(w + O_GO);
        ushort* sp = (ushort*)(w + O_SP);

        hipMemsetAsync(cnt, 0, 512000, stream);
        hist_kernel<<<(NB * NF / 4 + 255) / 256, 256, 0, stream>>>(gid, cnt);
        scan_rank_kernel<<<NB, 256, 0, stream>>>(cnt, pk, cursor, gorder);
        invperm_kernel<<<NB * 4, 256, 0, stream>>>(gid, cursor, sp);
        pool_kernel<<<NB * (NC / CPB), 1024, 0, stream>>>(fe, sp, pk, gorder, out);
    } else {
        pool_fused_kernel<<<NB * NC, 256, 0, stream>>>(fe, gid, out);
    }
}